// Round 8
// baseline (241.400 us; speedup 1.0000x reference)
//
#include <hip/hip_runtime.h>
#include <hip/hip_bf16.h>

using bf16 = __hip_bfloat16;
typedef __attribute__((ext_vector_type(8))) short short8;   // 8 bf16 = 4 VGPRs (MFMA A/B frag)
typedef __attribute__((ext_vector_type(4))) float f32x4;    // MFMA C/D frag

#define MFMA16(a, b, c) __builtin_amdgcn_mfma_f32_16x16x32_bf16((a), (b), (c), 0, 0, 0)

// async 16B global->LDS (HW: wave-uniform LDS base + lane*16; per-lane ptr must match)
__device__ inline void async16(bf16* lds, const bf16* g) {
  __builtin_amdgcn_global_load_lds(
      (const __attribute__((address_space(1))) void*)g,
      (__attribute__((address_space(3))) void*)lds, 16, 0, 0);
}

// single fused fp32->bf16 conversion for x + 4 weight matrices (float4 granules)
__global__ __launch_bounds__(256) void cvt_all(
    const float* __restrict__ x,  const float* __restrict__ Wq,
    const float* __restrict__ Wk, const float* __restrict__ Wv,
    const float* __restrict__ Wo,
    bf16* __restrict__ xb, bf16* __restrict__ Wqb, bf16* __restrict__ Wkb,
    bf16* __restrict__ Wvb, bf16* __restrict__ Wob) {
  int i = blockIdx.x * 256 + threadIdx.x;
  const float* s; bf16* d; int off;
  if (i < 1048576)      { s = x;  d = xb;  off = i; }
  else if (i < 1310720) { s = Wq; d = Wqb; off = i - 1048576; }
  else if (i < 1572864) { s = Wk; d = Wkb; off = i - 1310720; }
  else if (i < 1835008) { s = Wv; d = Wvb; off = i - 1572864; }
  else                  { s = Wo; d = Wob; off = i - 1835008; }
  float4 v = ((const float4*)s)[off];
  struct __align__(8) B4 { bf16 a, b, c, d; };
  B4 o{__float2bfloat16(v.x), __float2bfloat16(v.y),
       __float2bfloat16(v.z), __float2bfloat16(v.w)};
  *(B4*)&d[(size_t)off * 4] = o;
}

// Fused QKV GEMM -> Q/K [B,H,2048,64], V^T [B,H,64,2048]. grid (32, 24).
// Q region pre-scaled by 0.125*asc[h]*log2(e) (attn softmax is max-free exp2).
__global__ __launch_bounds__(256) void gemm_qkv(
    const bf16* __restrict__ A,
    const bf16* __restrict__ Wq, const bf16* __restrict__ Wk, const bf16* __restrict__ Wv,
    const float* __restrict__ bq, const float* __restrict__ bk, const float* __restrict__ bv,
    const float* __restrict__ asc,
    bf16* __restrict__ Qb, bf16* __restrict__ Kb, bf16* __restrict__ Vtb) {
  __shared__ __align__(16) bf16 As[128 * 32];
  __shared__ __align__(16) bf16 Bs[128 * 32];

  const int tid = threadIdx.x;
  const int lane = tid & 63;
  const int w = tid >> 6;
  const int m0 = blockIdx.x * 128;
  const int region = blockIdx.y >> 3;
  const int n0loc = (blockIdx.y & 7) * 128;
  const int wm = (w >> 1) * 64;
  const int wn = (w & 1) * 64;
  const int rq = lane & 15;
  const int quad = lane >> 4;
  const int kq = quad * 8;

  const bf16* W = region == 0 ? Wq : (region == 1 ? Wk : Wv);
  const float* bias = region == 0 ? bq : (region == 1 ? bk : bv);
  bf16* C = region == 0 ? Qb : (region == 1 ? Kb : Vtb);

  f32x4 acc[4][4] = {};
  const bf16* Ag = A + (size_t)m0 * 1024;
  const bf16* Wg = W + (size_t)n0loc * 1024;

  for (int k0 = 0; k0 < 1024; k0 += 32) {
    __syncthreads();
#pragma unroll
    for (int rep = 0; rep < 2; ++rep) {
      int c = tid + rep * 256;
      int row = c >> 2;
      int ce = (c & 3) * 8;
      async16(&As[c * 8], Ag + (size_t)row * 1024 + k0 + ce);
      async16(&Bs[c * 8], Wg + (size_t)row * 1024 + k0 + ce);
    }
    __syncthreads();

    short8 a[4], b[4];
#pragma unroll
    for (int i = 0; i < 4; ++i) a[i] = *(const short8*)&As[(wm + i * 16 + rq) * 32 + kq];
#pragma unroll
    for (int j = 0; j < 4; ++j) b[j] = *(const short8*)&Bs[(wn + j * 16 + rq) * 32 + kq];
#pragma unroll
    for (int i = 0; i < 4; ++i)
#pragma unroll
      for (int j = 0; j < 4; ++j) acc[i][j] = MFMA16(a[i], b[j], acc[i][j]);
  }

  const float LOG2E = 1.44269504088896f;
#pragma unroll
  for (int i = 0; i < 4; ++i)
#pragma unroll
    for (int j = 0; j < 4; ++j)
#pragma unroll
      for (int r2 = 0; r2 < 4; ++r2) {
        int m = m0 + wm + i * 16 + quad * 4 + r2;
        int nr = n0loc + wn + j * 16 + rq;
        int bb = m >> 11, t = m & 2047, h = nr >> 6, hd = nr & 63;
        float v = acc[i][j][r2] + bias[nr];
        if (region == 0) v *= 0.125f * asc[h] * LOG2E;   // fold softmax scale into Q
        bf16 ov = __float2bfloat16(v);
        if (region < 2)
          C[(((size_t)(bb * 16 + h)) * 2048 + t) * 64 + hd] = ov;
        else
          C[(((size_t)(bb * 16 + h)) * 64 + hd) * 2048 + t] = ov;
      }
}

// Out-proj GEMM + bias + residual (fp32 out)
__global__ __launch_bounds__(256) void gemm_out(
    const bf16* __restrict__ A, const bf16* __restrict__ W,
    const float* __restrict__ bias, const float* __restrict__ R,
    float* __restrict__ Y) {
  __shared__ __align__(16) bf16 As[128 * 32];
  __shared__ __align__(16) bf16 Bs[128 * 32];

  const int tid = threadIdx.x;
  const int lane = tid & 63;
  const int w = tid >> 6;
  const int m0 = blockIdx.x * 128;
  const int n0 = blockIdx.y * 128;
  const int wm = (w >> 1) * 64;
  const int wn = (w & 1) * 64;
  const int rq = lane & 15;
  const int quad = lane >> 4;
  const int kq = quad * 8;

  f32x4 acc[4][4] = {};
  const bf16* Ag = A + (size_t)m0 * 1024;
  const bf16* Wg = W + (size_t)n0 * 1024;

  for (int k0 = 0; k0 < 1024; k0 += 32) {
    __syncthreads();
#pragma unroll
    for (int rep = 0; rep < 2; ++rep) {
      int c = tid + rep * 256;
      int row = c >> 2;
      int ce = (c & 3) * 8;
      async16(&As[c * 8], Ag + (size_t)row * 1024 + k0 + ce);
      async16(&Bs[c * 8], Wg + (size_t)row * 1024 + k0 + ce);
    }
    __syncthreads();

    short8 a[4], b[4];
#pragma unroll
    for (int i = 0; i < 4; ++i) a[i] = *(const short8*)&As[(wm + i * 16 + rq) * 32 + kq];
#pragma unroll
    for (int j = 0; j < 4; ++j) b[j] = *(const short8*)&Bs[(wn + j * 16 + rq) * 32 + kq];
#pragma unroll
    for (int i = 0; i < 4; ++i)
#pragma unroll
      for (int j = 0; j < 4; ++j) acc[i][j] = MFMA16(a[i], b[j], acc[i][j]);
  }

#pragma unroll
  for (int i = 0; i < 4; ++i)
#pragma unroll
    for (int j = 0; j < 4; ++j)
#pragma unroll
      for (int r2 = 0; r2 < 4; ++r2) {
        int m = m0 + wm + i * 16 + quad * 4 + r2;
        int n = n0 + wn + j * 16 + rq;
        Y[(size_t)m * 1024 + n] = acc[i][j][r2] + bias[n] + R[(size_t)m * 1024 + n];
      }
}

// Flash attention v5: double-buffered async K/V staging, ONE barrier per
// K-tile (prefetch for kt+1 issued right after the barrier, drains at the
// NEXT barrier -> overlapped with the whole compute phase). 32 q-rows/wave,
// max-free exp2 softmax (Q pre-scaled to log2 domain), l via ones-MFMA,
// XOR-swizzled staging (conflict-free b128 frag reads).
#define LP 72
__global__ __launch_bounds__(256, 3) void attn_kernel(
    const bf16* __restrict__ Qb, const bf16* __restrict__ Kb,
    const bf16* __restrict__ Vtb, bf16* __restrict__ Ob) {
  __shared__ __align__(16) bf16 Ks[2][64 * 64];   // [buf][key][chunk^(key&7)]
  __shared__ __align__(16) bf16 Vs[2][64 * 64];   // [buf][d][chunk^(d&7)]
  __shared__ __align__(16) bf16 Ps[4][32 * LP];   // per-wave P [qrow][key], padded

  const int q0 = blockIdx.x * 128;
  const int h = blockIdx.y;
  const int b = blockIdx.z;
  const int tid = threadIdx.x;
  const int lane = tid & 63;
  const int w = tid >> 6;
  const int rq = lane & 15;
  const int quad = lane >> 4;
  const int kq = quad * 8;

  const size_t head = ((size_t)(b * 16 + h)) * 2048 * 64;
  const bf16* Qh = Qb + head;
  const bf16* Kh = Kb + head;
  const bf16* Vh = Vtb + head;   // [64][2048]

  // two 16-row Q A-frag sets per wave: rows q0 + w*32 + s*16 + rq
  short8 aq[2][2];
#pragma unroll
  for (int s = 0; s < 2; ++s) {
    const bf16* qrow = Qh + (size_t)(q0 + w * 32 + s * 16 + rq) * 64;
    aq[s][0] = *(const short8*)&qrow[kq];
    aq[s][1] = *(const short8*)&qrow[kq + 32];
  }

  short8 ones;
#pragma unroll
  for (int i = 0; i < 8; ++i) ones[i] = (short)0x3F80;   // bf16 1.0

  const int srow = lane >> 3;                     // 0..7
  const int sws = ((lane & 7) ^ srow) * 8;        // swizzled element offset in row
  const int c0 = (quad ^ (rq & 7)) * 8;           // frag-read swizzled chunk offset
  const int c1 = c0 ^ 32;

  // wave w stages K rows / V d-rows [w*16, w*16+16) in two 8-row async calls
  const int rb0 = w * 16;
  const int rb1 = w * 16 + 8;

  f32x4 accO[2][4] = {};
  f32x4 lacc[2] = {};

  // preload tile 0 into buffer 0
  {
    async16(&Ks[0][rb0 * 64 + lane * 8], Kh + (size_t)(rb0 + srow) * 64 + sws);
    async16(&Vs[0][rb0 * 64 + lane * 8], Vh + (size_t)(rb0 + srow) * 2048 + sws);
    async16(&Ks[0][rb1 * 64 + lane * 8], Kh + (size_t)(rb1 + srow) * 64 + sws);
    async16(&Vs[0][rb1 * 64 + lane * 8], Vh + (size_t)(rb1 + srow) * 2048 + sws);
  }

  for (int kt = 0; kt < 32; ++kt) {
    const int cur = kt & 1, nxt = cur ^ 1;
    // Single barrier: drains the prefetch targeting `cur` (issued one full
    // compute phase ago) AND guarantees all waves finished reading `nxt`'s
    // previous contents before we overwrite them below.
    __syncthreads();
    if (kt + 1 < 32) {
      int g = (kt + 1) * 64;
      async16(&Ks[nxt][rb0 * 64 + lane * 8], Kh + (size_t)(g + rb0 + srow) * 64 + sws);
      async16(&Vs[nxt][rb0 * 64 + lane * 8], Vh + (size_t)(rb0 + srow) * 2048 + g + sws);
      async16(&Ks[nxt][rb1 * 64 + lane * 8], Kh + (size_t)(g + rb1 + srow) * 64 + sws);
      async16(&Vs[nxt][rb1 * 64 + lane * 8], Vh + (size_t)(rb1 + srow) * 2048 + g + sws);
    }

    // t = Qs K^T for both row-sets; K fragments read once, used twice
    f32x4 S[2][4] = {};
#pragma unroll
    for (int j = 0; j < 4; ++j) {
      short8 bk0 = *(const short8*)&Ks[cur][(j * 16 + rq) * 64 + c0];
      short8 bk1 = *(const short8*)&Ks[cur][(j * 16 + rq) * 64 + c1];
      S[0][j] = MFMA16(aq[0][0], bk0, S[0][j]);
      S[0][j] = MFMA16(aq[0][1], bk1, S[0][j]);
      S[1][j] = MFMA16(aq[1][0], bk0, S[1][j]);
      S[1][j] = MFMA16(aq[1][1], bk1, S[1][j]);
    }

    // P = exp2(t) -> per-wave LDS (C-layout -> A-layout round trip; same-wave
    // write->read, ordered by lgkmcnt, no barrier needed)
#pragma unroll
    for (int s = 0; s < 2; ++s)
#pragma unroll
      for (int r = 0; r < 4; ++r)
#pragma unroll
        for (int j = 0; j < 4; ++j)
          Ps[w][(s * 16 + quad * 4 + r) * LP + j * 16 + rq] =
              __float2bfloat16(exp2f(S[s][j][r]));

    short8 ap[2][2];
#pragma unroll
    for (int s = 0; s < 2; ++s) {
      ap[s][0] = *(const short8*)&Ps[w][(s * 16 + rq) * LP + kq];
      ap[s][1] = *(const short8*)&Ps[w][(s * 16 + rq) * LP + kq + 32];
    }

    // O += P V ; l += P·1   (V fragments read once, used by both sets)
#pragma unroll
    for (int dt = 0; dt < 4; ++dt) {
      short8 bv0 = *(const short8*)&Vs[cur][(dt * 16 + rq) * 64 + c0];
      short8 bv1 = *(const short8*)&Vs[cur][(dt * 16 + rq) * 64 + c1];
#pragma unroll
      for (int s = 0; s < 2; ++s) {
        accO[s][dt] = MFMA16(ap[s][0], bv0, accO[s][dt]);
        accO[s][dt] = MFMA16(ap[s][1], bv1, accO[s][dt]);
      }
    }
#pragma unroll
    for (int s = 0; s < 2; ++s) {
      lacc[s] = MFMA16(ap[s][0], ones, lacc[s]);
      lacc[s] = MFMA16(ap[s][1], ones, lacc[s]);
    }
  }

#pragma unroll
  for (int s = 0; s < 2; ++s) {
    float rl[4];
#pragma unroll
    for (int r = 0; r < 4; ++r) rl[r] = 1.f / lacc[s][r];
#pragma unroll
    for (int dt = 0; dt < 4; ++dt)
#pragma unroll
      for (int r = 0; r < 4; ++r) {
        int t = q0 + w * 32 + s * 16 + quad * 4 + r;
        int d = dt * 16 + rq;
        Ob[((size_t)(b * 2048 + t)) * 1024 + h * 64 + d] =
            __float2bfloat16(accO[s][dt][r] * rl[r]);
      }
  }
}

// LayerNorm over D=1024 per row; all fp32
__global__ __launch_bounds__(256) void ln_kernel(
    const float* __restrict__ Y, const float* __restrict__ gamma,
    const float* __restrict__ beta, float* __restrict__ out) {
  const int row = blockIdx.x;
  const int tid = threadIdx.x;
  const int lane = tid & 63;
  const int w = tid >> 6;
  const float* y = Y + (size_t)row * 1024;

  float4 v = *(const float4*)&y[tid * 4];
  float s = v.x + v.y + v.z + v.w;
  float ss = v.x * v.x + v.y * v.y + v.z * v.z + v.w * v.w;
#pragma unroll
  for (int msk = 1; msk < 64; msk <<= 1) {
    s += __shfl_xor(s, msk);
    ss += __shfl_xor(ss, msk);
  }
  __shared__ float red[2][4];
  if (lane == 0) { red[0][w] = s; red[1][w] = ss; }
  __syncthreads();
  s = red[0][0] + red[0][1] + red[0][2] + red[0][3];
  ss = red[1][0] + red[1][1] + red[1][2] + red[1][3];
  float mean = s * (1.f / 1024.f);
  float var = ss * (1.f / 1024.f) - mean * mean;
  float rstd = rsqrtf(var + 1e-5f);
  float4 g = *(const float4*)&gamma[tid * 4];
  float4 bt = *(const float4*)&beta[tid * 4];
  float4 o;
  o.x = (v.x - mean) * rstd * g.x + bt.x;
  o.y = (v.y - mean) * rstd * g.y + bt.y;
  o.z = (v.z - mean) * rstd * g.z + bt.z;
  o.w = (v.w - mean) * rstd * g.w + bt.w;
  *(float4*)&out[(size_t)row * 1024 + tid * 4] = o;
}

extern "C" void kernel_launch(void* const* d_in, const int* in_sizes, int n_in,
                              void* d_out, int out_size, void* d_ws, size_t ws_size,
                              hipStream_t stream) {
  const float* x     = (const float*)d_in[0];
  const float* asc   = (const float*)d_in[1];
  const float* Wq    = (const float*)d_in[2];
  const float* bq    = (const float*)d_in[3];
  const float* Wk    = (const float*)d_in[4];
  const float* bk    = (const float*)d_in[5];
  const float* Wv    = (const float*)d_in[6];
  const float* bv    = (const float*)d_in[7];
  const float* Wo    = (const float*)d_in[8];
  const float* bo    = (const float*)d_in[9];
  const float* gamma = (const float*)d_in[10];
  const float* beta  = (const float*)d_in[11];
  float* out = (float*)d_out;

  char* ws = (char*)d_ws;
  const size_t MB = 1024 * 1024;
  bf16* Qb   = (bf16*)(ws);
  bf16* Kb   = (bf16*)(ws + 8 * MB);
  bf16* Vtb  = (bf16*)(ws + 16 * MB);
  bf16* attn = (bf16*)(ws + 24 * MB);
  bf16* xb   = (bf16*)(ws + 32 * MB);
  bf16* Wqb  = (bf16*)(ws + 40 * MB);
  bf16* Wkb  = (bf16*)(ws + 42 * MB);
  bf16* Wvb  = (bf16*)(ws + 44 * MB);
  bf16* Wob  = (bf16*)(ws + 46 * MB);
  float* y   = (float*)(ws);            // 16 MiB over dead Qb+Kb

  dim3 bb(256);

  cvt_all<<<dim3(8192), bb, 0, stream>>>(x, Wq, Wk, Wv, Wo, xb, Wqb, Wkb, Wvb, Wob);
  gemm_qkv<<<dim3(32, 24), bb, 0, stream>>>(xb, Wqb, Wkb, Wvb, bq, bk, bv, asc, Qb, Kb, Vtb);
  attn_kernel<<<dim3(16, 16, 2), bb, 0, stream>>>(Qb, Kb, Vtb, attn);
  gemm_out<<<dim3(32, 8), bb, 0, stream>>>(attn, Wob, bo, x, y);
  ln_kernel<<<dim3(4096), bb, 0, stream>>>(y, gamma, beta, out);
}

// Round 9
// 240.638 us; speedup vs baseline: 1.0032x; 1.0032x over previous
//
#include <hip/hip_runtime.h>
#include <hip/hip_bf16.h>

using bf16 = __hip_bfloat16;
typedef __attribute__((ext_vector_type(8))) short short8;   // 8 bf16 = 4 VGPRs (MFMA A/B frag)
typedef __attribute__((ext_vector_type(4))) float f32x4;    // MFMA C/D frag

#define MFMA16(a, b, c) __builtin_amdgcn_mfma_f32_16x16x32_bf16((a), (b), (c), 0, 0, 0)

// async 16B global->LDS (HW: wave-uniform LDS base + lane*16; per-lane ptr must match)
__device__ inline void async16(bf16* lds, const bf16* g) {
  __builtin_amdgcn_global_load_lds(
      (const __attribute__((address_space(1))) void*)g,
      (__attribute__((address_space(3))) void*)lds, 16, 0, 0);
}

// single fused fp32->bf16 conversion for x + 4 weight matrices (float4 granules)
__global__ __launch_bounds__(256) void cvt_all(
    const float* __restrict__ x,  const float* __restrict__ Wq,
    const float* __restrict__ Wk, const float* __restrict__ Wv,
    const float* __restrict__ Wo,
    bf16* __restrict__ xb, bf16* __restrict__ Wqb, bf16* __restrict__ Wkb,
    bf16* __restrict__ Wvb, bf16* __restrict__ Wob) {
  int i = blockIdx.x * 256 + threadIdx.x;
  const float* s; bf16* d; int off;
  if (i < 1048576)      { s = x;  d = xb;  off = i; }
  else if (i < 1310720) { s = Wq; d = Wqb; off = i - 1048576; }
  else if (i < 1572864) { s = Wk; d = Wkb; off = i - 1310720; }
  else if (i < 1835008) { s = Wv; d = Wvb; off = i - 1572864; }
  else                  { s = Wo; d = Wob; off = i - 1835008; }
  float4 v = ((const float4*)s)[off];
  struct __align__(8) B4 { bf16 a, b, c, d; };
  B4 o{__float2bfloat16(v.x), __float2bfloat16(v.y),
       __float2bfloat16(v.z), __float2bfloat16(v.w)};
  *(B4*)&d[(size_t)off * 4] = o;
}

// Fused QKV GEMM -> Q/K [B,H,2048,64], V^T [B,H,64,2048]. grid (32, 24).
// Q region pre-scaled by 0.125*asc[h]*log2(e) (attn softmax is max-free exp2).
__global__ __launch_bounds__(256) void gemm_qkv(
    const bf16* __restrict__ A,
    const bf16* __restrict__ Wq, const bf16* __restrict__ Wk, const bf16* __restrict__ Wv,
    const float* __restrict__ bq, const float* __restrict__ bk, const float* __restrict__ bv,
    const float* __restrict__ asc,
    bf16* __restrict__ Qb, bf16* __restrict__ Kb, bf16* __restrict__ Vtb) {
  __shared__ __align__(16) bf16 As[128 * 32];
  __shared__ __align__(16) bf16 Bs[128 * 32];

  const int tid = threadIdx.x;
  const int lane = tid & 63;
  const int w = tid >> 6;
  const int m0 = blockIdx.x * 128;
  const int region = blockIdx.y >> 3;
  const int n0loc = (blockIdx.y & 7) * 128;
  const int wm = (w >> 1) * 64;
  const int wn = (w & 1) * 64;
  const int rq = lane & 15;
  const int quad = lane >> 4;
  const int kq = quad * 8;

  const bf16* W = region == 0 ? Wq : (region == 1 ? Wk : Wv);
  const float* bias = region == 0 ? bq : (region == 1 ? bk : bv);
  bf16* C = region == 0 ? Qb : (region == 1 ? Kb : Vtb);

  f32x4 acc[4][4] = {};
  const bf16* Ag = A + (size_t)m0 * 1024;
  const bf16* Wg = W + (size_t)n0loc * 1024;

  for (int k0 = 0; k0 < 1024; k0 += 32) {
    __syncthreads();
#pragma unroll
    for (int rep = 0; rep < 2; ++rep) {
      int c = tid + rep * 256;
      int row = c >> 2;
      int ce = (c & 3) * 8;
      async16(&As[c * 8], Ag + (size_t)row * 1024 + k0 + ce);
      async16(&Bs[c * 8], Wg + (size_t)row * 1024 + k0 + ce);
    }
    __syncthreads();

    short8 a[4], b[4];
#pragma unroll
    for (int i = 0; i < 4; ++i) a[i] = *(const short8*)&As[(wm + i * 16 + rq) * 32 + kq];
#pragma unroll
    for (int j = 0; j < 4; ++j) b[j] = *(const short8*)&Bs[(wn + j * 16 + rq) * 32 + kq];
#pragma unroll
    for (int i = 0; i < 4; ++i)
#pragma unroll
      for (int j = 0; j < 4; ++j) acc[i][j] = MFMA16(a[i], b[j], acc[i][j]);
  }

  const float LOG2E = 1.44269504088896f;
#pragma unroll
  for (int i = 0; i < 4; ++i)
#pragma unroll
    for (int j = 0; j < 4; ++j)
#pragma unroll
      for (int r2 = 0; r2 < 4; ++r2) {
        int m = m0 + wm + i * 16 + quad * 4 + r2;
        int nr = n0loc + wn + j * 16 + rq;
        int bb = m >> 11, t = m & 2047, h = nr >> 6, hd = nr & 63;
        float v = acc[i][j][r2] + bias[nr];
        if (region == 0) v *= 0.125f * asc[h] * LOG2E;   // fold softmax scale into Q
        bf16 ov = __float2bfloat16(v);
        if (region < 2)
          C[(((size_t)(bb * 16 + h)) * 2048 + t) * 64 + hd] = ov;
        else
          C[(((size_t)(bb * 16 + h)) * 64 + hd) * 2048 + t] = ov;
      }
}

// Out-proj GEMM + bias + residual (fp32 out)
__global__ __launch_bounds__(256) void gemm_out(
    const bf16* __restrict__ A, const bf16* __restrict__ W,
    const float* __restrict__ bias, const float* __restrict__ R,
    float* __restrict__ Y) {
  __shared__ __align__(16) bf16 As[128 * 32];
  __shared__ __align__(16) bf16 Bs[128 * 32];

  const int tid = threadIdx.x;
  const int lane = tid & 63;
  const int w = tid >> 6;
  const int m0 = blockIdx.x * 128;
  const int n0 = blockIdx.y * 128;
  const int wm = (w >> 1) * 64;
  const int wn = (w & 1) * 64;
  const int rq = lane & 15;
  const int quad = lane >> 4;
  const int kq = quad * 8;

  f32x4 acc[4][4] = {};
  const bf16* Ag = A + (size_t)m0 * 1024;
  const bf16* Wg = W + (size_t)n0 * 1024;

  for (int k0 = 0; k0 < 1024; k0 += 32) {
    __syncthreads();
#pragma unroll
    for (int rep = 0; rep < 2; ++rep) {
      int c = tid + rep * 256;
      int row = c >> 2;
      int ce = (c & 3) * 8;
      async16(&As[c * 8], Ag + (size_t)row * 1024 + k0 + ce);
      async16(&Bs[c * 8], Wg + (size_t)row * 1024 + k0 + ce);
    }
    __syncthreads();

    short8 a[4], b[4];
#pragma unroll
    for (int i = 0; i < 4; ++i) a[i] = *(const short8*)&As[(wm + i * 16 + rq) * 32 + kq];
#pragma unroll
    for (int j = 0; j < 4; ++j) b[j] = *(const short8*)&Bs[(wn + j * 16 + rq) * 32 + kq];
#pragma unroll
    for (int i = 0; i < 4; ++i)
#pragma unroll
      for (int j = 0; j < 4; ++j) acc[i][j] = MFMA16(a[i], b[j], acc[i][j]);
  }

#pragma unroll
  for (int i = 0; i < 4; ++i)
#pragma unroll
    for (int j = 0; j < 4; ++j)
#pragma unroll
      for (int r2 = 0; r2 < 4; ++r2) {
        int m = m0 + wm + i * 16 + quad * 4 + r2;
        int n = n0 + wn + j * 16 + rq;
        Y[(size_t)m * 1024 + n] = acc[i][j][r2] + bias[n] + R[(size_t)m * 1024 + n];
      }
}

// Flash attention v6: K-SPLIT x2 (flash-decoding). Max-free softmax makes
// partials combine LINEARLY: O = O0+O1, l = l0+l1 -> no rescale pass.
// grid (16 qtiles, 16 heads, 2 batch x 2 ksplit) = 1024 blocks = 4/CU
// = 16 waves/CU (TLP hides the barrier vmcnt drain). 32 q-rows/wave,
// single-buffered swizzled async staging (R6 structure).
#define LP 72
__global__ __launch_bounds__(256, 3) void attn_kernel(
    const bf16* __restrict__ Qb, const bf16* __restrict__ Kb,
    const bf16* __restrict__ Vtb,
    bf16* __restrict__ P0, bf16* __restrict__ P1, float* __restrict__ lbuf) {
  __shared__ __align__(16) bf16 Ks[64 * 64];      // [key][chunk^(key&7)] swizzled
  __shared__ __align__(16) bf16 Vs[64 * 64];      // [d][chunk^(d&7)] swizzled
  __shared__ __align__(16) bf16 Ps[4][32 * LP];   // per-wave P [qrow][key], padded

  const int q0 = blockIdx.x * 128;
  const int h = blockIdx.y;
  const int b = blockIdx.z & 1;
  const int half = blockIdx.z >> 1;
  const int tid = threadIdx.x;
  const int lane = tid & 63;
  const int w = tid >> 6;
  const int rq = lane & 15;
  const int quad = lane >> 4;
  const int kq = quad * 8;

  const size_t head = ((size_t)(b * 16 + h)) * 2048 * 64;
  const bf16* Qh = Qb + head;
  const bf16* Kh = Kb + head;
  const bf16* Vh = Vtb + head;   // [64][2048]

  // two 16-row Q A-frag sets per wave: rows q0 + w*32 + s*16 + rq
  short8 aq[2][2];
#pragma unroll
  for (int s = 0; s < 2; ++s) {
    const bf16* qrow = Qh + (size_t)(q0 + w * 32 + s * 16 + rq) * 64;
    aq[s][0] = *(const short8*)&qrow[kq];
    aq[s][1] = *(const short8*)&qrow[kq + 32];
  }

  short8 ones;
#pragma unroll
  for (int i = 0; i < 8; ++i) ones[i] = (short)0x3F80;   // bf16 1.0

  const int srow = lane >> 3;                     // 0..7
  const int sws = ((lane & 7) ^ srow) * 8;        // swizzled element offset in row
  const int c0 = (quad ^ (rq & 7)) * 8;           // frag-read swizzled chunk offset
  const int c1 = c0 ^ 32;

  f32x4 accO[2][4] = {};
  f32x4 lacc[2] = {};

  const int kt0 = half * 16;
  for (int kt = kt0; kt < kt0 + 16; ++kt) {
    __syncthreads();
#pragma unroll
    for (int t = 0; t < 2; ++t) {
      int rb = w * 16 + t * 8;
      int row = rb + srow;
      async16(&Ks[rb * 64 + lane * 8], Kh + (size_t)(kt * 64 + row) * 64 + sws);
      async16(&Vs[rb * 64 + lane * 8], Vh + (size_t)row * 2048 + kt * 64 + sws);
    }
    __syncthreads();

    // t = Qs K^T for both row-sets; K fragments read once, used twice
    f32x4 S[2][4] = {};
#pragma unroll
    for (int j = 0; j < 4; ++j) {
      short8 bk0 = *(const short8*)&Ks[(j * 16 + rq) * 64 + c0];
      short8 bk1 = *(const short8*)&Ks[(j * 16 + rq) * 64 + c1];
      S[0][j] = MFMA16(aq[0][0], bk0, S[0][j]);
      S[0][j] = MFMA16(aq[0][1], bk1, S[0][j]);
      S[1][j] = MFMA16(aq[1][0], bk0, S[1][j]);
      S[1][j] = MFMA16(aq[1][1], bk1, S[1][j]);
    }

    // P = exp2(t) -> per-wave LDS (C-layout -> A-layout round trip)
#pragma unroll
    for (int s = 0; s < 2; ++s)
#pragma unroll
      for (int r = 0; r < 4; ++r)
#pragma unroll
        for (int j = 0; j < 4; ++j)
          Ps[w][(s * 16 + quad * 4 + r) * LP + j * 16 + rq] =
              __float2bfloat16(exp2f(S[s][j][r]));

    short8 ap[2][2];
#pragma unroll
    for (int s = 0; s < 2; ++s) {
      ap[s][0] = *(const short8*)&Ps[w][(s * 16 + rq) * LP + kq];
      ap[s][1] = *(const short8*)&Ps[w][(s * 16 + rq) * LP + kq + 32];
    }

    // O += P V ; l += P·1   (V fragments read once, used by both sets)
#pragma unroll
    for (int dt = 0; dt < 4; ++dt) {
      short8 bv0 = *(const short8*)&Vs[(dt * 16 + rq) * 64 + c0];
      short8 bv1 = *(const short8*)&Vs[(dt * 16 + rq) * 64 + c1];
#pragma unroll
      for (int s = 0; s < 2; ++s) {
        accO[s][dt] = MFMA16(ap[s][0], bv0, accO[s][dt]);
        accO[s][dt] = MFMA16(ap[s][1], bv1, accO[s][dt]);
      }
    }
#pragma unroll
    for (int s = 0; s < 2; ++s) {
      lacc[s] = MFMA16(ap[s][0], ones, lacc[s]);
      lacc[s] = MFMA16(ap[s][1], ones, lacc[s]);
    }
  }

  // epilogue: UNNORMALIZED partial O (bf16) + partial l (fp32)
  bf16* Pout = half ? P1 : P0;
  float* lout = lbuf + half * 65536;
#pragma unroll
  for (int s = 0; s < 2; ++s) {
#pragma unroll
    for (int dt = 0; dt < 4; ++dt)
#pragma unroll
      for (int r = 0; r < 4; ++r) {
        int t = q0 + w * 32 + s * 16 + quad * 4 + r;
        int d = dt * 16 + rq;
        Pout[((size_t)(b * 2048 + t)) * 1024 + h * 64 + d] =
            __float2bfloat16(accO[s][dt][r]);
      }
    if (rq == 0) {
#pragma unroll
      for (int r = 0; r < 4; ++r) {
        int t = q0 + w * 32 + s * 16 + quad * 4 + r;
        lout[(b * 16 + h) * 2048 + t] = lacc[s][r];
      }
    }
  }
}

// Combine K-split partials: attn = (P0 + P1) / (l0 + l1)   (in-place over P0)
__global__ __launch_bounds__(256) void combine_kernel(
    bf16* __restrict__ P0, const bf16* __restrict__ P1,
    const float* __restrict__ lbuf) {
  const int row = blockIdx.x;            // 0..4095 = b*2048 + t
  const int tid = threadIdx.x;
  const int col = tid * 4;               // 4 bf16 per thread
  const int b = row >> 11, t = row & 2047;
  const int h = col >> 6;
  const float l = lbuf[(b * 16 + h) * 2048 + t] + lbuf[65536 + (b * 16 + h) * 2048 + t];
  const float rl = 1.f / l;
  size_t base = (size_t)row * 1024 + col;
  struct __align__(8) B4 { bf16 a, b, c, d; };
  B4 p0 = *(const B4*)&P0[base];
  B4 p1 = *(const B4*)&P1[base];
  B4 o;
  o.a = __float2bfloat16((__bfloat162float(p0.a) + __bfloat162float(p1.a)) * rl);
  o.b = __float2bfloat16((__bfloat162float(p0.b) + __bfloat162float(p1.b)) * rl);
  o.c = __float2bfloat16((__bfloat162float(p0.c) + __bfloat162float(p1.c)) * rl);
  o.d = __float2bfloat16((__bfloat162float(p0.d) + __bfloat162float(p1.d)) * rl);
  *(B4*)&P0[base] = o;
}

// LayerNorm over D=1024 per row; all fp32
__global__ __launch_bounds__(256) void ln_kernel(
    const float* __restrict__ Y, const float* __restrict__ gamma,
    const float* __restrict__ beta, float* __restrict__ out) {
  const int row = blockIdx.x;
  const int tid = threadIdx.x;
  const int lane = tid & 63;
  const int w = tid >> 6;
  const float* y = Y + (size_t)row * 1024;

  float4 v = *(const float4*)&y[tid * 4];
  float s = v.x + v.y + v.z + v.w;
  float ss = v.x * v.x + v.y * v.y + v.z * v.z + v.w * v.w;
#pragma unroll
  for (int msk = 1; msk < 64; msk <<= 1) {
    s += __shfl_xor(s, msk);
    ss += __shfl_xor(ss, msk);
  }
  __shared__ float red[2][4];
  if (lane == 0) { red[0][w] = s; red[1][w] = ss; }
  __syncthreads();
  s = red[0][0] + red[0][1] + red[0][2] + red[0][3];
  ss = red[1][0] + red[1][1] + red[1][2] + red[1][3];
  float mean = s * (1.f / 1024.f);
  float var = ss * (1.f / 1024.f) - mean * mean;
  float rstd = rsqrtf(var + 1e-5f);
  float4 g = *(const float4*)&gamma[tid * 4];
  float4 bt = *(const float4*)&beta[tid * 4];
  float4 o;
  o.x = (v.x - mean) * rstd * g.x + bt.x;
  o.y = (v.y - mean) * rstd * g.y + bt.y;
  o.z = (v.z - mean) * rstd * g.z + bt.z;
  o.w = (v.w - mean) * rstd * g.w + bt.w;
  *(float4*)&out[(size_t)row * 1024 + tid * 4] = o;
}

extern "C" void kernel_launch(void* const* d_in, const int* in_sizes, int n_in,
                              void* d_out, int out_size, void* d_ws, size_t ws_size,
                              hipStream_t stream) {
  const float* x     = (const float*)d_in[0];
  const float* asc   = (const float*)d_in[1];
  const float* Wq    = (const float*)d_in[2];
  const float* bq    = (const float*)d_in[3];
  const float* Wk    = (const float*)d_in[4];
  const float* bk    = (const float*)d_in[5];
  const float* Wv    = (const float*)d_in[6];
  const float* bv    = (const float*)d_in[7];
  const float* Wo    = (const float*)d_in[8];
  const float* bo    = (const float*)d_in[9];
  const float* gamma = (const float*)d_in[10];
  const float* beta  = (const float*)d_in[11];
  float* out = (float*)d_out;

  // ws (48 MiB):
  //  [0,8M)   Qb           (after attn: dead; y fp32 [0,16M) aliases Qb+Kb)
  //  [8,16M)  Kb
  //  [16,24M) Vtb
  //  [24,32M) attn / P0    (K-split partial 0; combine normalizes in-place)
  //  [32,40M) xb / P1      (xb dead after gemm_qkv -> partial 1)
  //  [40,42M) Wqb / lbuf   (dead after gemm_qkv -> l partials, 512KB)
  //  [42,44M) Wkb  [44,46M) Wvb  [46,48M) Wob (live until gemm_out)
  char* ws = (char*)d_ws;
  const size_t MB = 1024 * 1024;
  bf16* Qb   = (bf16*)(ws);
  bf16* Kb   = (bf16*)(ws + 8 * MB);
  bf16* Vtb  = (bf16*)(ws + 16 * MB);
  bf16* attn = (bf16*)(ws + 24 * MB);   // P0
  bf16* xb   = (bf16*)(ws + 32 * MB);   // P1 after gemm_qkv
  bf16* Wqb  = (bf16*)(ws + 40 * MB);   // lbuf after gemm_qkv
  bf16* Wkb  = (bf16*)(ws + 42 * MB);
  bf16* Wvb  = (bf16*)(ws + 44 * MB);
  bf16* Wob  = (bf16*)(ws + 46 * MB);
  float* y   = (float*)(ws);            // 16 MiB over dead Qb+Kb
  bf16* P1   = xb;
  float* lbuf = (float*)Wqb;

  dim3 bb(256);

  cvt_all<<<dim3(8192), bb, 0, stream>>>(x, Wq, Wk, Wv, Wo, xb, Wqb, Wkb, Wvb, Wob);
  gemm_qkv<<<dim3(32, 24), bb, 0, stream>>>(xb, Wqb, Wkb, Wvb, bq, bk, bv, asc, Qb, Kb, Vtb);
  attn_kernel<<<dim3(16, 16, 4), bb, 0, stream>>>(Qb, Kb, Vtb, attn, P1, lbuf);
  combine_kernel<<<dim3(4096), bb, 0, stream>>>(attn, P1, lbuf);
  gemm_out<<<dim3(32, 8), bb, 0, stream>>>(attn, Wob, bo, x, y);
  ln_kernel<<<dim3(4096), bb, 0, stream>>>(y, gamma, beta, out);
}

// Round 10
// 226.302 us; speedup vs baseline: 1.0667x; 1.0634x over previous
//
#include <hip/hip_runtime.h>
#include <hip/hip_bf16.h>

using bf16 = __hip_bfloat16;
typedef __attribute__((ext_vector_type(8))) short short8;   // 8 bf16 (MFMA A/B frag)
typedef __attribute__((ext_vector_type(4))) short short4v;  // 4 bf16 = b64
typedef __attribute__((ext_vector_type(4))) float f32x4;    // MFMA C/D frag

#define MFMA16(a, b, c) __builtin_amdgcn_mfma_f32_16x16x32_bf16((a), (b), (c), 0, 0, 0)

__device__ inline void async16(bf16* lds, const bf16* g) {
  __builtin_amdgcn_global_load_lds(
      (const __attribute__((address_space(1))) void*)g,
      (__attribute__((address_space(3))) void*)lds, 16, 0, 0);
}

__device__ inline short bfs(float x) {
  union { bf16 h; short s; } u; u.h = __float2bfloat16(x); return u.s;
}
__device__ inline short4v pack4(float a, float b, float c, float d) {
  short4v r; r[0] = bfs(a); r[1] = bfs(b); r[2] = bfs(c); r[3] = bfs(d); return r;
}

// fused fp32->bf16 conversion for x + 4 weight matrices
__global__ __launch_bounds__(256) void cvt_all(
    const float* __restrict__ x,  const float* __restrict__ Wq,
    const float* __restrict__ Wk, const float* __restrict__ Wv,
    const float* __restrict__ Wo,
    bf16* __restrict__ xb, bf16* __restrict__ Wqb, bf16* __restrict__ Wkb,
    bf16* __restrict__ Wvb, bf16* __restrict__ Wob) {
  int i = blockIdx.x * 256 + threadIdx.x;
  const float* s; bf16* d; int off;
  if (i < 1048576)      { s = x;  d = xb;  off = i; }
  else if (i < 1310720) { s = Wq; d = Wqb; off = i - 1048576; }
  else if (i < 1572864) { s = Wk; d = Wkb; off = i - 1310720; }
  else if (i < 1835008) { s = Wv; d = Wvb; off = i - 1572864; }
  else                  { s = Wo; d = Wob; off = i - 1835008; }
  float4 v = ((const float4*)s)[off];
  short4v o = pack4(v.x, v.y, v.z, v.w);
  *(short4v*)&d[(size_t)off * 4] = o;
}

// Fused QKV GEMM -> Q/K [B,H,2048,64], V^T [B,H,64,2048]. grid (32, 24).
// Q pre-scaled by 0.125*asc[h]*log2e. V^T epilogue: LDS-transposed b64 stores.
__global__ __launch_bounds__(256) void gemm_qkv(
    const bf16* __restrict__ A,
    const bf16* __restrict__ Wq, const bf16* __restrict__ Wk, const bf16* __restrict__ Wv,
    const float* __restrict__ bq, const float* __restrict__ bk, const float* __restrict__ bv,
    const float* __restrict__ asc,
    bf16* __restrict__ Qb, bf16* __restrict__ Kb, bf16* __restrict__ Vtb) {
  __shared__ __align__(16) bf16 As[128 * 32];
  __shared__ __align__(16) bf16 Bs[128 * 32];
  __shared__ __align__(16) bf16 scrT[4][16 * 68];   // per-wave V^T transpose scratch

  const int tid = threadIdx.x;
  const int lane = tid & 63;
  const int w = tid >> 6;
  const int m0 = blockIdx.x * 128;
  const int region = blockIdx.y >> 3;
  const int n0loc = (blockIdx.y & 7) * 128;
  const int wm = (w >> 1) * 64;
  const int wn = (w & 1) * 64;
  const int rq = lane & 15;
  const int quad = lane >> 4;
  const int kq = quad * 8;

  const bf16* W = region == 0 ? Wq : (region == 1 ? Wk : Wv);
  const float* bias = region == 0 ? bq : (region == 1 ? bk : bv);
  bf16* C = region == 0 ? Qb : (region == 1 ? Kb : Vtb);

  f32x4 acc[4][4] = {};
  const bf16* Ag = A + (size_t)m0 * 1024;
  const bf16* Wg = W + (size_t)n0loc * 1024;

  for (int k0 = 0; k0 < 1024; k0 += 32) {
    __syncthreads();
#pragma unroll
    for (int rep = 0; rep < 2; ++rep) {
      int c = tid + rep * 256;
      int row = c >> 2;
      int ce = (c & 3) * 8;
      async16(&As[c * 8], Ag + (size_t)row * 1024 + k0 + ce);
      async16(&Bs[c * 8], Wg + (size_t)row * 1024 + k0 + ce);
    }
    __syncthreads();

    short8 a[4], b[4];
#pragma unroll
    for (int i = 0; i < 4; ++i) a[i] = *(const short8*)&As[(wm + i * 16 + rq) * 32 + kq];
#pragma unroll
    for (int j = 0; j < 4; ++j) b[j] = *(const short8*)&Bs[(wn + j * 16 + rq) * 32 + kq];
#pragma unroll
    for (int i = 0; i < 4; ++i)
#pragma unroll
      for (int j = 0; j < 4; ++j) acc[i][j] = MFMA16(a[i], b[j], acc[i][j]);
  }

  const float LOG2E = 1.44269504088896f;
  if (region < 2) {
#pragma unroll
    for (int i = 0; i < 4; ++i)
#pragma unroll
      for (int j = 0; j < 4; ++j)
#pragma unroll
        for (int r2 = 0; r2 < 4; ++r2) {
          int m = m0 + wm + i * 16 + quad * 4 + r2;
          int nr = n0loc + wn + j * 16 + rq;
          int bb = m >> 11, t = m & 2047, h = nr >> 6, hd = nr & 63;
          float v = acc[i][j][r2] + bias[nr];
          if (region == 0) v *= 0.125f * asc[h] * LOG2E;
          C[(((size_t)(bb * 16 + h)) * 2048 + t) * 64 + hd] = __float2bfloat16(v);
        }
  } else {
    // V^T: per-wave transpose -> coalesced b64 stores along t
    const int bb = m0 >> 11;
    const int h = (n0loc + wn) >> 6;
    const int tbase = (m0 & 2047) + wm;
    bf16* scr = scrT[w];
#pragma unroll
    for (int j = 0; j < 4; ++j) {
      int nr = n0loc + wn + j * 16 + rq;
      float bi = bias[nr];
#pragma unroll
      for (int i = 0; i < 4; ++i) {
        short4v pv = pack4(acc[i][j][0] + bi, acc[i][j][1] + bi,
                           acc[i][j][2] + bi, acc[i][j][3] + bi);
        *(short4v*)&scr[rq * 68 + i * 16 + quad * 4] = pv;   // [q16=rq][p]
      }
      // same-wave write->read, lgkm-ordered
#pragma unroll
      for (int pp = 0; pp < 4; ++pp) {
        int hdl = pp * 4 + quad;
        short4v v4 = *(const short4v*)&scr[hdl * 68 + rq * 4];
        size_t addr = (((size_t)(bb * 16 + h)) * 64 + j * 16 + hdl) * 2048 + tbase + rq * 4;
        *(short4v*)&C[addr] = v4;
      }
    }
  }
}

// Out-proj GEMM + bias + residual (fp32 out)
__global__ __launch_bounds__(256) void gemm_out(
    const bf16* __restrict__ A, const bf16* __restrict__ W,
    const float* __restrict__ bias, const float* __restrict__ R,
    float* __restrict__ Y) {
  __shared__ __align__(16) bf16 As[128 * 32];
  __shared__ __align__(16) bf16 Bs[128 * 32];

  const int tid = threadIdx.x;
  const int lane = tid & 63;
  const int w = tid >> 6;
  const int m0 = blockIdx.x * 128;
  const int n0 = blockIdx.y * 128;
  const int wm = (w >> 1) * 64;
  const int wn = (w & 1) * 64;
  const int rq = lane & 15;
  const int quad = lane >> 4;
  const int kq = quad * 8;

  f32x4 acc[4][4] = {};
  const bf16* Ag = A + (size_t)m0 * 1024;
  const bf16* Wg = W + (size_t)n0 * 1024;

  for (int k0 = 0; k0 < 1024; k0 += 32) {
    __syncthreads();
#pragma unroll
    for (int rep = 0; rep < 2; ++rep) {
      int c = tid + rep * 256;
      int row = c >> 2;
      int ce = (c & 3) * 8;
      async16(&As[c * 8], Ag + (size_t)row * 1024 + k0 + ce);
      async16(&Bs[c * 8], Wg + (size_t)row * 1024 + k0 + ce);
    }
    __syncthreads();

    short8 a[4], b[4];
#pragma unroll
    for (int i = 0; i < 4; ++i) a[i] = *(const short8*)&As[(wm + i * 16 + rq) * 32 + kq];
#pragma unroll
    for (int j = 0; j < 4; ++j) b[j] = *(const short8*)&Bs[(wn + j * 16 + rq) * 32 + kq];
#pragma unroll
    for (int i = 0; i < 4; ++i)
#pragma unroll
      for (int j = 0; j < 4; ++j) acc[i][j] = MFMA16(a[i], b[j], acc[i][j]);
  }

#pragma unroll
  for (int i = 0; i < 4; ++i)
#pragma unroll
    for (int j = 0; j < 4; ++j)
#pragma unroll
      for (int r2 = 0; r2 < 4; ++r2) {
        int m = m0 + wm + i * 16 + quad * 4 + r2;
        int n = n0 + wn + j * 16 + rq;
        Y[(size_t)m * 1024 + n] = acc[i][j][r2] + bias[n] + R[(size_t)m * 1024 + n];
      }
}

// Flash attention v7: 64 q-rows/wave (4 sets sharing K/V frags), packed b64
// P writes via key-remapped S tiles (S-tile j columns = keys rq*4+j), K-split
// x2 with linear partial combine (max-free exp2 softmax, Q pre-scaled).
#define LP 72
__global__ __launch_bounds__(256, 2) void attn_kernel(
    const bf16* __restrict__ Qb, const bf16* __restrict__ Kb,
    const bf16* __restrict__ Vtb,
    bf16* __restrict__ P0, bf16* __restrict__ P1, float* __restrict__ lbuf) {
  __shared__ __align__(16) bf16 Ks[64 * 64];      // [key][chunk^(key&7)]
  __shared__ __align__(16) bf16 Vs[64 * 64];      // [d][chunk^(d&7)]
  __shared__ __align__(16) bf16 Ps[4][64 * LP];   // per-wave P [qrow][key]

  const int q0 = blockIdx.x * 256;
  const int h = blockIdx.y;
  const int b = blockIdx.z & 1;
  const int half = blockIdx.z >> 1;
  const int tid = threadIdx.x;
  const int lane = tid & 63;
  const int w = tid >> 6;
  const int rq = lane & 15;
  const int quad = lane >> 4;
  const int kq = quad * 8;

  const size_t head = ((size_t)(b * 16 + h)) * 2048 * 64;
  const bf16* Qh = Qb + head;
  const bf16* Kh = Kb + head;
  const bf16* Vh = Vtb + head;   // [64][2048]

  // four 16-row Q A-frag sets per wave: rows q0 + w*64 + s*16 + rq
  short8 aq[4][2];
#pragma unroll
  for (int s = 0; s < 4; ++s) {
    const bf16* qrow = Qh + (size_t)(q0 + w * 64 + s * 16 + rq) * 64;
    aq[s][0] = *(const short8*)&qrow[kq];
    aq[s][1] = *(const short8*)&qrow[kq + 32];
  }

  short8 ones;
#pragma unroll
  for (int i = 0; i < 8; ++i) ones[i] = (short)0x3F80;

  const int srow = lane >> 3;
  const int sws = ((lane & 7) ^ srow) * 8;        // staging swizzle
  const int c0 = (quad ^ (rq & 7)) * 8;           // V frag retrieval (rows dt*16+rq)
  const int c1 = c0 ^ 32;

  f32x4 accO[4][4] = {};
  f32x4 lacc[4] = {};

  const int kt0 = half * 16;
  for (int kt = kt0; kt < kt0 + 16; ++kt) {
    __syncthreads();
#pragma unroll
    for (int t = 0; t < 2; ++t) {
      int rb = w * 16 + t * 8;
      int row = rb + srow;
      async16(&Ks[rb * 64 + lane * 8], Kh + (size_t)(kt * 64 + row) * 64 + sws);
      async16(&Vs[rb * 64 + lane * 8], Vh + (size_t)row * 2048 + kt * 64 + sws);
    }
    __syncthreads();

    // K frags: S-tile j column n -> key n*4+j (read Ks rows rq*4+j).
    // Stored swizzle is chunk^(row&7); row&7 = 4*(rq&1)+j here.
    short8 bk[4][2];
#pragma unroll
    for (int j = 0; j < 4; ++j) {
      int sw = (quad ^ ((4 * (rq & 1) + j) & 7)) * 8;
      const bf16* kr = &Ks[(rq * 4 + j) * 64];
      bk[j][0] = *(const short8*)&kr[sw];
      bk[j][1] = *(const short8*)&kr[sw ^ 32];
    }

    // QK + exp2 + packed b64 P writes (Ps col p = key p, identity)
#pragma unroll
    for (int s = 0; s < 4; ++s) {
      f32x4 S[4] = {};
#pragma unroll
      for (int j = 0; j < 4; ++j) {
        S[j] = MFMA16(aq[s][0], bk[j][0], S[j]);
        S[j] = MFMA16(aq[s][1], bk[j][1], S[j]);
      }
#pragma unroll
      for (int r = 0; r < 4; ++r) {
        short4v pv = pack4(exp2f(S[0][r]), exp2f(S[1][r]),
                           exp2f(S[2][r]), exp2f(S[3][r]));
        *(short4v*)&Ps[w][(s * 16 + quad * 4 + r) * LP + rq * 4] = pv;
      }
    }

    // V frags (natural key order), then PV + l per set
    short8 bv[4][2];
#pragma unroll
    for (int dt = 0; dt < 4; ++dt) {
      const bf16* vr = &Vs[(dt * 16 + rq) * 64];
      bv[dt][0] = *(const short8*)&vr[c0];
      bv[dt][1] = *(const short8*)&vr[c1];
    }
#pragma unroll
    for (int s = 0; s < 4; ++s) {
      short8 ap0 = *(const short8*)&Ps[w][(s * 16 + rq) * LP + kq];
      short8 ap1 = *(const short8*)&Ps[w][(s * 16 + rq) * LP + kq + 32];
#pragma unroll
      for (int dt = 0; dt < 4; ++dt) {
        accO[s][dt] = MFMA16(ap0, bv[dt][0], accO[s][dt]);
        accO[s][dt] = MFMA16(ap1, bv[dt][1], accO[s][dt]);
      }
      lacc[s] = MFMA16(ap0, ones, lacc[s]);
      lacc[s] = MFMA16(ap1, ones, lacc[s]);
    }
  }

  // epilogue: UNNORMALIZED partial O (bf16) + partial l (fp32)
  bf16* Pout = half ? P1 : P0;
  float* lout = lbuf + half * 65536;
#pragma unroll
  for (int s = 0; s < 4; ++s) {
#pragma unroll
    for (int dt = 0; dt < 4; ++dt)
#pragma unroll
      for (int r = 0; r < 4; ++r) {
        int t = q0 + w * 64 + s * 16 + quad * 4 + r;
        int d = dt * 16 + rq;
        Pout[((size_t)(b * 2048 + t)) * 1024 + h * 64 + d] =
            __float2bfloat16(accO[s][dt][r]);
      }
    if (rq == 0) {
#pragma unroll
      for (int r = 0; r < 4; ++r) {
        int t = q0 + w * 64 + s * 16 + quad * 4 + r;
        lout[(b * 16 + h) * 2048 + t] = lacc[s][r];
      }
    }
  }
}

// Combine K-split partials: attn = (P0 + P1) / (l0 + l1)   (in-place over P0)
__global__ __launch_bounds__(256) void combine_kernel(
    bf16* __restrict__ P0, const bf16* __restrict__ P1,
    const float* __restrict__ lbuf) {
  const int row = blockIdx.x;
  const int tid = threadIdx.x;
  const int col = tid * 4;
  const int b = row >> 11, t = row & 2047;
  const int h = col >> 6;
  const float l = lbuf[(b * 16 + h) * 2048 + t] + lbuf[65536 + (b * 16 + h) * 2048 + t];
  const float rl = 1.f / l;
  size_t base = (size_t)row * 1024 + col;
  short4v p0 = *(const short4v*)&P0[base];
  short4v p1 = *(const short4v*)&P1[base];
  union { short s; bf16 h; } u;
  float v[4];
#pragma unroll
  for (int i = 0; i < 4; ++i) {
    u.s = p0[i]; float a = __bfloat162float(u.h);
    u.s = p1[i]; float c = __bfloat162float(u.h);
    v[i] = (a + c) * rl;
  }
  *(short4v*)&P0[base] = pack4(v[0], v[1], v[2], v[3]);
}

// LayerNorm over D=1024 per row; all fp32
__global__ __launch_bounds__(256) void ln_kernel(
    const float* __restrict__ Y, const float* __restrict__ gamma,
    const float* __restrict__ beta, float* __restrict__ out) {
  const int row = blockIdx.x;
  const int tid = threadIdx.x;
  const int lane = tid & 63;
  const int w = tid >> 6;
  const float* y = Y + (size_t)row * 1024;

  float4 v = *(const float4*)&y[tid * 4];
  float s = v.x + v.y + v.z + v.w;
  float ss = v.x * v.x + v.y * v.y + v.z * v.z + v.w * v.w;
#pragma unroll
  for (int msk = 1; msk < 64; msk <<= 1) {
    s += __shfl_xor(s, msk);
    ss += __shfl_xor(ss, msk);
  }
  __shared__ float red[2][4];
  if (lane == 0) { red[0][w] = s; red[1][w] = ss; }
  __syncthreads();
  s = red[0][0] + red[0][1] + red[0][2] + red[0][3];
  ss = red[1][0] + red[1][1] + red[1][2] + red[1][3];
  float mean = s * (1.f / 1024.f);
  float var = ss * (1.f / 1024.f) - mean * mean;
  float rstd = rsqrtf(var + 1e-5f);
  float4 g = *(const float4*)&gamma[tid * 4];
  float4 bt = *(const float4*)&beta[tid * 4];
  float4 o;
  o.x = (v.x - mean) * rstd * g.x + bt.x;
  o.y = (v.y - mean) * rstd * g.y + bt.y;
  o.z = (v.z - mean) * rstd * g.z + bt.z;
  o.w = (v.w - mean) * rstd * g.w + bt.w;
  *(float4*)&out[(size_t)row * 1024 + tid * 4] = o;
}

extern "C" void kernel_launch(void* const* d_in, const int* in_sizes, int n_in,
                              void* d_out, int out_size, void* d_ws, size_t ws_size,
                              hipStream_t stream) {
  const float* x     = (const float*)d_in[0];
  const float* asc   = (const float*)d_in[1];
  const float* Wq    = (const float*)d_in[2];
  const float* bq    = (const float*)d_in[3];
  const float* Wk    = (const float*)d_in[4];
  const float* bk    = (const float*)d_in[5];
  const float* Wv    = (const float*)d_in[6];
  const float* bv    = (const float*)d_in[7];
  const float* Wo    = (const float*)d_in[8];
  const float* bo    = (const float*)d_in[9];
  const float* gamma = (const float*)d_in[10];
  const float* beta  = (const float*)d_in[11];
  float* out = (float*)d_out;

  char* ws = (char*)d_ws;
  const size_t MB = 1024 * 1024;
  bf16* Qb   = (bf16*)(ws);
  bf16* Kb   = (bf16*)(ws + 8 * MB);
  bf16* Vtb  = (bf16*)(ws + 16 * MB);
  bf16* attn = (bf16*)(ws + 24 * MB);   // P0
  bf16* xb   = (bf16*)(ws + 32 * MB);   // P1 after gemm_qkv
  bf16* Wqb  = (bf16*)(ws + 40 * MB);   // lbuf after gemm_qkv
  bf16* Wkb  = (bf16*)(ws + 42 * MB);
  bf16* Wvb  = (bf16*)(ws + 44 * MB);
  bf16* Wob  = (bf16*)(ws + 46 * MB);
  float* y   = (float*)(ws);            // 16 MiB over dead Qb+Kb
  bf16* P1   = xb;
  float* lbuf = (float*)Wqb;

  dim3 bb(256);

  cvt_all<<<dim3(8192), bb, 0, stream>>>(x, Wq, Wk, Wv, Wo, xb, Wqb, Wkb, Wvb, Wob);
  gemm_qkv<<<dim3(32, 24), bb, 0, stream>>>(xb, Wqb, Wkb, Wvb, bq, bk, bv, asc, Qb, Kb, Vtb);
  attn_kernel<<<dim3(8, 16, 4), bb, 0, stream>>>(Qb, Kb, Vtb, attn, P1, lbuf);
  combine_kernel<<<dim3(4096), bb, 0, stream>>>(attn, P1, lbuf);
  gemm_out<<<dim3(32, 8), bb, 0, stream>>>(attn, Wob, bo, x, y);
  ln_kernel<<<dim3(4096), bb, 0, stream>>>(y, gamma, beta, out);
}